// Round 9
// baseline (971.972 us; speedup 1.0000x reference)
//
#include <hip/hip_runtime.h>

#define LL 4096
#define NB 4
#define NC 64
#define NT 4
#define NLAYERS 10
#define XS 5120   // padded x row stride
#define XPAD 512  // left/right zero pad (>= max dilation)

typedef float v2f __attribute__((ext_vector_type(2)));

// ---------------- Threefry-2x32, key = (0, 42), 20 rounds ----------------
__device__ __forceinline__ void threefry2x32(unsigned x0, unsigned x1,
                                             unsigned& o0, unsigned& o1) {
  const unsigned ks0 = 0u, ks1 = 42u;
  const unsigned ks2 = 0x1BD11BDAu ^ ks0 ^ ks1;
  const unsigned ks[3] = {ks0, ks1, ks2};
  const unsigned r0[4] = {13u, 15u, 26u, 6u};
  const unsigned r1[4] = {17u, 29u, 16u, 24u};
  x0 += ks0; x1 += ks1;
#pragma unroll
  for (int g = 0; g < 5; ++g) {
    const unsigned* rr = (g & 1) ? r1 : r0;
#pragma unroll
    for (int j = 0; j < 4; ++j) {
      x0 += x1;
      unsigned r = rr[j];
      x1 = (x1 << r) | (x1 >> (32u - r));
      x1 ^= x0;
    }
    x0 += ks[(g + 1) % 3];
    x1 += ks[(g + 2) % 3] + (unsigned)(g + 1);
  }
  o0 = x0; o1 = x1;
}

__device__ __forceinline__ float u01(unsigned bits) {
  return __uint_as_float((bits >> 9) | 0x3f800000u) - 1.0f;
}

// LIF step: v = v + (x - v)/1.2 ; spike = v>=0.5 ; v *= (1-spike)
__device__ __forceinline__ float lif_step(float& v, float xt) {
  v = v + (xt - v) / 1.2f;
  float s = (v >= 0.5f) ? 1.0f : 0.0f;
  v = v * (1.0f - s);
  return s;
}

// ---------------- prep: transpose skip/res 1x1 + build wT ----------------
// skipT/resT: [i][c'][c]. wT: [i][g][ci][k][col16], col<8 gate co=g*8+col,
// col>=8 filt co=64+g*8+col-8.
__global__ void prep_kernel(const float* __restrict__ skip_w,
                            const float* __restrict__ res_w,
                            const float* __restrict__ conv_w,
                            float* __restrict__ skipT,
                            float* __restrict__ resT,
                            float* __restrict__ wT) {
  int i = blockIdx.x;
  for (int idx = threadIdx.x; idx < 4096; idx += 256) {
    int c = idx >> 6, cp = idx & 63;
    skipT[i * 4096 + cp * 64 + c] = skip_w[i * 4096 + c * 64 + cp];
    resT[i * 4096 + cp * 64 + c] = res_w[i * 4096 + c * 64 + cp];
  }
  for (int idx = threadIdx.x; idx < 8 * 64 * 3 * 16; idx += 256) {
    int col = idx & 15;
    int r = idx >> 4;
    int k = r % 3; r /= 3;
    int ci = r % 64;
    int g = r / 64;
    int co = (col < 8) ? (g * 8 + col) : (64 + g * 8 + (col - 8));
    wT[i * 24576 + idx] = conv_w[(i * 128 + co) * 192 + ci * 3 + k];
  }
}

// ---------------- diffusion-step embedding -> proj[i][b][c] ----------------
__global__ void proj_kernel(const int* __restrict__ dstep,
                            const float* __restrict__ w1, const float* __restrict__ b1,
                            const float* __restrict__ w2, const float* __restrict__ b2,
                            const float* __restrict__ pw, const float* __restrict__ pb,
                            float* __restrict__ proj) {
  __shared__ float e1[NB][NC];
  __shared__ float e2[NB][NC];
  int i = blockIdx.x;
  int tid = threadIdx.x;
  int b = tid >> 6, c = tid & 63;
  float d = (float)dstep[b];
  float v = d * w1[i * 64 + c] + b1[i * 64 + c];
  v = v / (1.0f + expf(-v));  // silu
  e1[b][c] = v;
  __syncthreads();
  float a = b2[i * 64 + c];
  for (int cp = 0; cp < 64; ++cp) a += e1[b][cp] * w2[(i * 64 + c) * 64 + cp];
  e2[b][c] = a;
  __syncthreads();
  float p = pb[i * 64 + c];
  for (int cp = 0; cp < 64; ++cp) p += e2[b][cp] * pw[(i * 64 + c) * 64 + cp];
  proj[(i * 4 + b) * 64 + c] = p;
}

// ---------------- per-(layer,b,co) proj-weighted tap sums S0,S1,S2 ----------------
__global__ void pc_kernel(const float* __restrict__ proj,
                          const float* __restrict__ conv_w,
                          float* __restrict__ pc) {
  __shared__ float pv[64];
  int layer = blockIdx.x, b = blockIdx.y;
  int tid = threadIdx.x;  // 128
  if (tid < 64) pv[tid] = proj[(layer * 4 + b) * 64 + tid];
  __syncthreads();
  int co = tid;
  const float* w = conv_w + (layer * 128 + co) * 192;
  float s0 = 0.0f, s1 = 0.0f, s2 = 0.0f;
  for (int ci = 0; ci < 64; ++ci) {
    float p = pv[ci];
    s0 += p * w[ci * 3 + 0];
    s1 += p * w[ci * 3 + 1];
    s2 += p * w[ci * 3 + 2];
  }
  float* o = pc + ((layer * 4 + b) * 128 + co) * 3;
  o[0] = s0; o[1] = s1; o[2] = s2;
}

// ---------------- zero the pad margins of x (ws is poisoned every call) ---------
__global__ void padzero_kernel(float* __restrict__ x) {
  int row = blockIdx.x;  // 1024 rows = T*B*C
  float* base = x + (size_t)row * XS;
  for (int i = threadIdx.x; i < XPAD; i += 256) {
    base[i] = 0.0f;
    base[XPAD + LL + i] = 0.0f;
  }
}

// ---------------- Poisson encode + input conv + LIF -> x [T][B][C][XS] ---------
__global__ void encode_lif_kernel(const float* __restrict__ audio,
                                  const float* __restrict__ W_in,
                                  const float* __restrict__ b_in,
                                  float* __restrict__ x) {
  int tid = threadIdx.x;
  int lq = tid & 63, grp = tid >> 6;
  int l = blockIdx.x * 64 + lq;
  int b = blockIdx.y;
  float a = audio[b * LL + l];
  unsigned p0 = (unsigned)(b * LL + l);  // t=0 (o0), t=2 (o1)
  unsigned p1 = 16384u + p0;             // t=1 (o0), t=3 (o1)
  unsigned o00, o01, o10, o11;
  threefry2x32(p0, p0 + 32768u, o00, o01);
  threefry2x32(p1, p1 + 32768u, o10, o11);
  float sp[4];
  sp[0] = (u01(o00) < a) ? 1.0f : 0.0f;
  sp[1] = (u01(o10) < a) ? 1.0f : 0.0f;
  sp[2] = (u01(o01) < a) ? 1.0f : 0.0f;
  sp[3] = (u01(o11) < a) ? 1.0f : 0.0f;
  for (int j = 0; j < 16; ++j) {
    int c = grp * 16 + j;
    float w = W_in[c], bb = b_in[c];
    float v = 0.0f;
#pragma unroll
    for (int t = 0; t < 4; ++t) {
      float s = lif_step(v, w * sp[t] + bb);
      x[(size_t)((t * 4 + b) * 64 + c) * XS + XPAD + l] = s;
    }
  }
}

// ---------------- dilated conv + LIF + gate -> y [T][B][64][L] ----------------
// grid (16, 8, 4): l-tile 256, co-group g, b. block 256 -> 2 waves/SIMD
// (structural). launch_bounds(256,2) raises VGPR cap to 256: full ci-
// distance-1 weight double-buffer (12 float4/ci) + 2-deep x prefetch.
// Weight delivery rebalanced: k0 plane (4 b128) from LDS, k1/k2 (8 float4)
// from global uniform -> LDS pipe @8 waves = 4*12*8 = 384 cyc/ci = VALU wall.
// FMA inner loop: v_pk_fma_f32, identical arithmetic order to R8 (absmax 0).
template <int DIL>
__global__ __launch_bounds__(256, 2) void layer_conv_kernel(
    const float* __restrict__ x, const float* __restrict__ wT,
    const float* __restrict__ conv_b, const float* __restrict__ pc,
    float* __restrict__ y, int layer) {
  __shared__ float wg_lds[64 * 16];  // k=0 plane: [ci][col16], 4 KB
  int tid = threadIdx.x;
  int g = blockIdx.y;
  int b = blockIdx.z;
  int l = blockIdx.x * 256 + tid;
  const float* wbase = wT + (size_t)(layer * 8 + g) * 3072;  // [ci][k][16]

  for (int idx = tid; idx < 1024; idx += 256) {
    // LDS [ci][c16] <- wT [ci][k=0][c16]
    wg_lds[idx] = wbase[(idx >> 4) * 48 + (idx & 15)];
  }
  __syncthreads();

  const float* px[4];
#pragma unroll
  for (int t = 0; t < 4; ++t)
    px[t] = x + (size_t)((t * 4 + b) * 64) * XS + XPAD + l;

  v2f ag[16], af[16];  // [t*4 + pair], pair p covers co j=2p,2p+1
#pragma unroll
  for (int q = 0; q < 16; ++q) {
    ag[q] = (v2f)(0.0f);
    af[q] = (v2f)(0.0f);
  }

  float xa[12], xb[12];    // [t*3+k]
  float4 wA[12], wB[12];   // per ci: [k][4] = gate0-3,gate4-7,filt0-3,filt4-7
  auto loadx = [&](float* dst) {
#pragma unroll
    for (int t = 0; t < 4; ++t) {
      dst[t * 3 + 0] = px[t][-DIL];
      dst[t * 3 + 1] = px[t][0];
      dst[t * 3 + 2] = px[t][DIL];
      px[t] += XS;
    }
  };
  auto loadw = [&](float4* w, int ci) {
    const float4* p0 = (const float4*)&wg_lds[ci * 16];        // k=0 from LDS
#pragma unroll
    for (int q = 0; q < 4; ++q) w[q] = p0[q];
    const float4* p1 = (const float4*)&wbase[ci * 48 + 16];    // k=1,2 global
#pragma unroll
    for (int q = 0; q < 8; ++q) w[4 + q] = p1[q];
  };
  auto compute = [&](const float* xv, const float4* w) {
#pragma unroll
    for (int k = 0; k < 3; ++k) {
      const v2f* wk = (const v2f*)&w[k * 4];  // gate 0..3, filt 4..7
#pragma unroll
      for (int t = 0; t < 4; ++t) {
        float xq = xv[t * 3 + k];
        v2f x2;
        x2.x = xq; x2.y = xq;
        ag[t * 4 + 0] += wk[0] * x2;
        ag[t * 4 + 1] += wk[1] * x2;
        ag[t * 4 + 2] += wk[2] * x2;
        ag[t * 4 + 3] += wk[3] * x2;
        af[t * 4 + 0] += wk[4] * x2;
        af[t * 4 + 1] += wk[5] * x2;
        af[t * 4 + 2] += wk[6] * x2;
        af[t * 4 + 3] += wk[7] * x2;
      }
    }
  };

  loadw(wA, 0);
  loadx(xa);
  for (int ci = 0; ci < 64; ci += 2) {
    loadw(wB, ci + 1);
    loadx(xb);
    compute(xa, wA);
    if (ci + 2 < 64) { loadw(wA, ci + 2); loadx(xa); }
    compute(xb, wB);
  }

  const float SIG1 = 0.73105857863000489f;   // sigmoid(1) fp32
  const float TANH1 = 0.76159415595576486f;  // tanh(1) fp32
  bool lb = (l < DIL), rb = (l >= LL - DIL);
#pragma unroll
  for (int j = 0; j < 8; ++j) {
    int cog = g * 8 + j;
    int cof = 64 + g * 8 + j;
    const float* pg = pc + ((layer * 4 + b) * 128 + cog) * 3;
    const float* pf = pc + ((layer * 4 + b) * 128 + cof) * 3;
    float S0g = pg[0], S1g = pg[1], S2g = pg[2];
    float S0f = pf[0], S1f = pf[1], S2f = pf[2];
    float bg = conv_b[layer * 128 + cog] + S0g + S1g + S2g;
    float bf = conv_b[layer * 128 + cof] + S0f + S1f + S2f;
    bg -= (lb ? S0g : 0.0f) + (rb ? S2g : 0.0f);
    bf -= (lb ? S0f : 0.0f) + (rb ? S2f : 0.0f);
    float vg = 0.0f, vf = 0.0f;
#pragma unroll
    for (int t = 0; t < 4; ++t) {
      float av = ag[t * 4 + (j >> 1)][j & 1];
      float fv = af[t * 4 + (j >> 1)][j & 1];
      float sg = lif_step(vg, av + bg);
      float sf = lif_step(vf, fv + bf);
      float gv = (sg != 0.0f) ? SIG1 : 0.5f;
      float tv = (sf != 0.0f) ? TANH1 : 0.0f;
      y[(size_t)((t * 4 + b) * 64 + cog) * LL + l] = gv * tv;
    }
  }
}

// ---------------- 1x1 skip / res convs ----------------
// grid (16, 2, 16): l-tile 256, cv (0=skip,1=res), tb. block 256.
// Thread: 8 c x 8 l register tile; pk_fma; distance-2 double-buffer on
// weights + y (stall/cp ~136 -> ~70 cyc). Sequential cp order. No LDS.
__global__ __launch_bounds__(256, 2) void skip_res_kernel(
    const float* __restrict__ y, const float* __restrict__ skipT,
    const float* __restrict__ resT, const float* __restrict__ skip_b,
    const float* __restrict__ res_b, float* __restrict__ tskip,
    float* __restrict__ x, int layer) {
  int tid = threadIdx.x;
  int lg = tid & 31;   // 32 l-groups of 8 (coalesced across lanes)
  int cg = tid >> 5;   // 8 c-groups of 8
  int cv = blockIdx.y;
  int tb = blockIdx.z;
  int l0 = blockIdx.x * 256 + lg * 8;
  int c0 = cg * 8;

  const float* wsrc = (cv ? resT : skipT) + layer * 4096 + c0;  // [cp][c]
  const float* yb = y + (size_t)tb * 64 * LL + l0;

  v2f acc[32];  // [c8][l-pair4]
#pragma unroll
  for (int q = 0; q < 32; ++q) acc[q] = (v2f)(0.0f);

  float4 wA[2], yA[2], wB[2], yB[2];
  auto loadyw = [&](float4* wb, float4* yb2, int cp) {
    wb[0] = *(const float4*)&wsrc[cp * 64];
    wb[1] = *(const float4*)&wsrc[cp * 64 + 4];
    yb2[0] = *(const float4*)&yb[(size_t)cp * LL];
    yb2[1] = *(const float4*)&yb[(size_t)cp * LL + 4];
  };
  auto compute = [&](const float4* wb, const float4* yb2) {
    float wv[8] = {wb[0].x, wb[0].y, wb[0].z, wb[0].w,
                   wb[1].x, wb[1].y, wb[1].z, wb[1].w};
    const v2f* yv = (const v2f*)yb2;  // 4 v2f
#pragma unroll
    for (int i = 0; i < 8; ++i) {
      v2f w2;
      w2.x = wv[i]; w2.y = wv[i];
      acc[i * 4 + 0] += w2 * yv[0];
      acc[i * 4 + 1] += w2 * yv[1];
      acc[i * 4 + 2] += w2 * yv[2];
      acc[i * 4 + 3] += w2 * yv[3];
    }
  };

  loadyw(wA, yA, 0);
  loadyw(wB, yB, 1);
  for (int cp = 0; cp < 64; cp += 2) {
    compute(wA, yA);
    if (cp + 2 < 64) loadyw(wA, yA, cp + 2);
    compute(wB, yB);
    if (cp + 3 < 64) loadyw(wB, yB, cp + 3);
  }

  const float* bsrc = (cv ? res_b : skip_b) + layer * 64 + c0;
#pragma unroll
  for (int i = 0; i < 8; ++i) {
    float bb = bsrc[i];
    float r[8];
#pragma unroll
    for (int j = 0; j < 8; ++j) r[j] = acc[i * 4 + (j >> 1)][j & 1] + bb;
    if (cv == 0) {
      size_t idx = (size_t)(tb * 64 + c0 + i) * LL + l0;
      float4 o0, o1;
      if (layer == 0) {
        o0.x = o0.y = o0.z = o0.w = 0.0f;
        o1 = o0;
      } else {
        o0 = *(const float4*)&tskip[idx];
        o1 = *(const float4*)&tskip[idx + 4];
      }
      o0.x += r[0]; o0.y += r[1]; o0.z += r[2]; o0.w += r[3];
      o1.x += r[4]; o1.y += r[5]; o1.z += r[6]; o1.w += r[7];
      *(float4*)&tskip[idx] = o0;
      *(float4*)&tskip[idx + 4] = o1;
    } else {
      size_t idx = (size_t)(tb * 64 + c0 + i) * XS + XPAD + l0;
      float4 o0 = *(const float4*)&x[idx];
      float4 o1 = *(const float4*)&x[idx + 4];
      o0.x += r[0]; o0.y += r[1]; o0.z += r[2]; o0.w += r[3];
      o1.x += r[4]; o1.y += r[5]; o1.z += r[6]; o1.w += r[7];
      *(float4*)&x[idx] = o0;
      *(float4*)&x[idx + 4] = o1;
    }
  }
}

// ---------------- output conv + LIF + sum over T ----------------
__global__ void out_kernel(const float* __restrict__ tskip,
                           const float* __restrict__ W_out,
                           const float* __restrict__ b_out,
                           float* __restrict__ out) {
  __shared__ float red[4][4][64];  // [grp][t][lq]
  int tid = threadIdx.x;
  int lq = tid & 63, grp = tid >> 6;
  int l = blockIdx.x * 64 + lq;
  int b = blockIdx.y;
  float acc[4] = {0.0f, 0.0f, 0.0f, 0.0f};
  for (int j = 0; j < 16; ++j) {
    int c = grp * 16 + j;
    float w = W_out[c];
#pragma unroll
    for (int t = 0; t < 4; ++t) {
      float sv = tskip[(size_t)((t * 4 + b) * 64 + c) * LL + l];
      acc[t] += fmaxf(sv, 0.0f) * w;
    }
  }
#pragma unroll
  for (int t = 0; t < 4; ++t) red[grp][t][lq] = acc[t];
  __syncthreads();
  if (grp == 0) {
    float bo = b_out[0];
    float v = 0.0f, s = 0.0f;
#pragma unroll
    for (int t = 0; t < 4; ++t) {
      float a = red[0][t][lq] + red[1][t][lq] + red[2][t][lq] + red[3][t][lq] + bo;
      s += lif_step(v, a);
    }
    out[b * LL + l] = s;
  }
}

extern "C" void kernel_launch(void* const* d_in, const int* in_sizes, int n_in,
                              void* d_out, int out_size, void* d_ws, size_t ws_size,
                              hipStream_t stream) {
  const float* audio   = (const float*)d_in[0];
  const int*   dstep   = (const int*)d_in[1];
  const float* W_in    = (const float*)d_in[2];
  const float* b_in    = (const float*)d_in[3];
  const float* demb_w1 = (const float*)d_in[4];
  const float* demb_b1 = (const float*)d_in[5];
  const float* demb_w2 = (const float*)d_in[6];
  const float* demb_b2 = (const float*)d_in[7];
  const float* dproj_w = (const float*)d_in[8];
  const float* dproj_b = (const float*)d_in[9];
  const float* conv_w  = (const float*)d_in[10];
  const float* conv_b  = (const float*)d_in[11];
  const float* skip_w  = (const float*)d_in[12];
  const float* skip_b  = (const float*)d_in[13];
  const float* res_w   = (const float*)d_in[14];
  const float* res_b   = (const float*)d_in[15];
  const float* W_out   = (const float*)d_in[16];
  const float* b_out   = (const float*)d_in[17];
  float* out = (float*)d_out;
  float* ws = (float*)d_ws;

  float* proj  = ws;                   // 2560
  float* skipT = proj + 2560;          // 40960
  float* resT  = skipT + 40960;        // 40960
  float* pc    = resT + 40960;         // 15360
  float* wT    = pc + 15360;           // 10*8*64*48 = 245760
  float* x     = wT + 245760;          // 4*4*64*5120 = 5242880
  float* y     = x + 5242880;          // 4194304
  float* tskip = y + 4194304;          // 4194304

  prep_kernel<<<10, 256, 0, stream>>>(skip_w, res_w, conv_w, skipT, resT, wT);
  proj_kernel<<<10, 256, 0, stream>>>(dstep, demb_w1, demb_b1, demb_w2, demb_b2,
                                      dproj_w, dproj_b, proj);
  pc_kernel<<<dim3(10, 4), 128, 0, stream>>>(proj, conv_w, pc);
  padzero_kernel<<<1024, 256, 0, stream>>>(x);
  encode_lif_kernel<<<dim3(64, 4), 256, 0, stream>>>(audio, W_in, b_in, x);

  for (int i = 0; i < NLAYERS; ++i) {
    dim3 gc(16, 8, 4);
    switch (i) {
      case 0: layer_conv_kernel<1><<<gc, 256, 0, stream>>>(x, wT, conv_b, pc, y, i); break;
      case 1: layer_conv_kernel<2><<<gc, 256, 0, stream>>>(x, wT, conv_b, pc, y, i); break;
      case 2: layer_conv_kernel<4><<<gc, 256, 0, stream>>>(x, wT, conv_b, pc, y, i); break;
      case 3: layer_conv_kernel<8><<<gc, 256, 0, stream>>>(x, wT, conv_b, pc, y, i); break;
      case 4: layer_conv_kernel<16><<<gc, 256, 0, stream>>>(x, wT, conv_b, pc, y, i); break;
      case 5: layer_conv_kernel<32><<<gc, 256, 0, stream>>>(x, wT, conv_b, pc, y, i); break;
      case 6: layer_conv_kernel<64><<<gc, 256, 0, stream>>>(x, wT, conv_b, pc, y, i); break;
      case 7: layer_conv_kernel<128><<<gc, 256, 0, stream>>>(x, wT, conv_b, pc, y, i); break;
      case 8: layer_conv_kernel<256><<<gc, 256, 0, stream>>>(x, wT, conv_b, pc, y, i); break;
      case 9: layer_conv_kernel<512><<<gc, 256, 0, stream>>>(x, wT, conv_b, pc, y, i); break;
    }
    skip_res_kernel<<<dim3(16, 2, 16), 256, 0, stream>>>(y, skipT, resT, skip_b,
                                                         res_b, tskip, x, i);
  }
  out_kernel<<<dim3(64, 4), 256, 0, stream>>>(tskip, W_out, b_out, out);
}

// Round 10
// 838.206 us; speedup vs baseline: 1.1596x; 1.1596x over previous
//
#include <hip/hip_runtime.h>

#define LL 4096
#define NB 4
#define NC 64
#define NT 4
#define NLAYERS 10
#define XS 5120   // padded x row stride (in l units; x is [B][C][XS][4])
#define XPAD 512  // left/right zero pad (>= max dilation)

typedef float v2f __attribute__((ext_vector_type(2)));

// ---------------- Threefry-2x32, key = (0, 42), 20 rounds ----------------
__device__ __forceinline__ void threefry2x32(unsigned x0, unsigned x1,
                                             unsigned& o0, unsigned& o1) {
  const unsigned ks0 = 0u, ks1 = 42u;
  const unsigned ks2 = 0x1BD11BDAu ^ ks0 ^ ks1;
  const unsigned ks[3] = {ks0, ks1, ks2};
  const unsigned r0[4] = {13u, 15u, 26u, 6u};
  const unsigned r1[4] = {17u, 29u, 16u, 24u};
  x0 += ks0; x1 += ks1;
#pragma unroll
  for (int g = 0; g < 5; ++g) {
    const unsigned* rr = (g & 1) ? r1 : r0;
#pragma unroll
    for (int j = 0; j < 4; ++j) {
      x0 += x1;
      unsigned r = rr[j];
      x1 = (x1 << r) | (x1 >> (32u - r));
      x1 ^= x0;
    }
    x0 += ks[(g + 1) % 3];
    x1 += ks[(g + 2) % 3] + (unsigned)(g + 1);
  }
  o0 = x0; o1 = x1;
}

__device__ __forceinline__ float u01(unsigned bits) {
  return __uint_as_float((bits >> 9) | 0x3f800000u) - 1.0f;
}

// LIF step: v = v + (x - v)/1.2 ; spike = v>=0.5 ; v *= (1-spike)
__device__ __forceinline__ float lif_step(float& v, float xt) {
  v = v + (xt - v) / 1.2f;
  float s = (v >= 0.5f) ? 1.0f : 0.0f;
  v = v * (1.0f - s);
  return s;
}

// ---------------- prep: transpose skip/res 1x1 + build wT ----------------
// skipT/resT: [i][c'][c]. wT: [i][g][ci][k][col16], col<8 gate co=g*8+col,
// col>=8 filt co=64+g*8+col-8.
__global__ void prep_kernel(const float* __restrict__ skip_w,
                            const float* __restrict__ res_w,
                            const float* __restrict__ conv_w,
                            float* __restrict__ skipT,
                            float* __restrict__ resT,
                            float* __restrict__ wT) {
  int i = blockIdx.x;
  for (int idx = threadIdx.x; idx < 4096; idx += 256) {
    int c = idx >> 6, cp = idx & 63;
    skipT[i * 4096 + cp * 64 + c] = skip_w[i * 4096 + c * 64 + cp];
    resT[i * 4096 + cp * 64 + c] = res_w[i * 4096 + c * 64 + cp];
  }
  for (int idx = threadIdx.x; idx < 8 * 64 * 3 * 16; idx += 256) {
    int col = idx & 15;
    int r = idx >> 4;
    int k = r % 3; r /= 3;
    int ci = r % 64;
    int g = r / 64;
    int co = (col < 8) ? (g * 8 + col) : (64 + g * 8 + (col - 8));
    wT[i * 24576 + idx] = conv_w[(i * 128 + co) * 192 + ci * 3 + k];
  }
}

// ---------------- diffusion-step embedding -> proj[i][b][c] ----------------
__global__ void proj_kernel(const int* __restrict__ dstep,
                            const float* __restrict__ w1, const float* __restrict__ b1,
                            const float* __restrict__ w2, const float* __restrict__ b2,
                            const float* __restrict__ pw, const float* __restrict__ pb,
                            float* __restrict__ proj) {
  __shared__ float e1[NB][NC];
  __shared__ float e2[NB][NC];
  int i = blockIdx.x;
  int tid = threadIdx.x;
  int b = tid >> 6, c = tid & 63;
  float d = (float)dstep[b];
  float v = d * w1[i * 64 + c] + b1[i * 64 + c];
  v = v / (1.0f + expf(-v));  // silu
  e1[b][c] = v;
  __syncthreads();
  float a = b2[i * 64 + c];
  for (int cp = 0; cp < 64; ++cp) a += e1[b][cp] * w2[(i * 64 + c) * 64 + cp];
  e2[b][c] = a;
  __syncthreads();
  float p = pb[i * 64 + c];
  for (int cp = 0; cp < 64; ++cp) p += e2[b][cp] * pw[(i * 64 + c) * 64 + cp];
  proj[(i * 4 + b) * 64 + c] = p;
}

// ---------------- per-(layer,b,co) proj-weighted tap sums S0,S1,S2 ----------------
__global__ void pc_kernel(const float* __restrict__ proj,
                          const float* __restrict__ conv_w,
                          float* __restrict__ pc) {
  __shared__ float pv[64];
  int layer = blockIdx.x, b = blockIdx.y;
  int tid = threadIdx.x;  // 128
  if (tid < 64) pv[tid] = proj[(layer * 4 + b) * 64 + tid];
  __syncthreads();
  int co = tid;
  const float* w = conv_w + (layer * 128 + co) * 192;
  float s0 = 0.0f, s1 = 0.0f, s2 = 0.0f;
  for (int ci = 0; ci < 64; ++ci) {
    float p = pv[ci];
    s0 += p * w[ci * 3 + 0];
    s1 += p * w[ci * 3 + 1];
    s2 += p * w[ci * 3 + 2];
  }
  float* o = pc + ((layer * 4 + b) * 128 + co) * 3;
  o[0] = s0; o[1] = s1; o[2] = s2;
}

// ---------------- zero the pad margins of x (ws is poisoned every call) ---------
__global__ void padzero_kernel(float* __restrict__ x) {
  int row = blockIdx.x;  // 256 rows = B*C
  float* base = x + (size_t)row * XS * 4;
  for (int i = threadIdx.x; i < XPAD; i += 256) {
    *(float4*)&base[i * 4] = float4{0.f, 0.f, 0.f, 0.f};
    *(float4*)&base[(XPAD + LL + i) * 4] = float4{0.f, 0.f, 0.f, 0.f};
  }
}

// ---------------- Poisson encode + input conv + LIF -> x [B][C][XS][4] ---------
__global__ void encode_lif_kernel(const float* __restrict__ audio,
                                  const float* __restrict__ W_in,
                                  const float* __restrict__ b_in,
                                  float* __restrict__ x) {
  int tid = threadIdx.x;
  int lq = tid & 63, grp = tid >> 6;
  int l = blockIdx.x * 64 + lq;
  int b = blockIdx.y;
  float a = audio[b * LL + l];
  unsigned p0 = (unsigned)(b * LL + l);  // t=0 (o0), t=2 (o1)
  unsigned p1 = 16384u + p0;             // t=1 (o0), t=3 (o1)
  unsigned o00, o01, o10, o11;
  threefry2x32(p0, p0 + 32768u, o00, o01);
  threefry2x32(p1, p1 + 32768u, o10, o11);
  float sp[4];
  sp[0] = (u01(o00) < a) ? 1.0f : 0.0f;
  sp[1] = (u01(o10) < a) ? 1.0f : 0.0f;
  sp[2] = (u01(o01) < a) ? 1.0f : 0.0f;
  sp[3] = (u01(o11) < a) ? 1.0f : 0.0f;
  for (int j = 0; j < 16; ++j) {
    int c = grp * 16 + j;
    float w = W_in[c], bb = b_in[c];
    float v = 0.0f;
    float4 o;
    float* op = (float*)&o;
#pragma unroll
    for (int t = 0; t < 4; ++t) op[t] = lif_step(v, w * sp[t] + bb);
    *(float4*)&x[(size_t)((b * 64 + c) * XS + XPAD + l) * 4] = o;
  }
}

// ---------------- dilated conv + LIF + gate -> y [B][64][LL][4] ----------------
// grid (16, 8, 4): l-tile 256, co-group g, b. block 256. Thread: 1 l, 4 t
// (vectorized in x/y layout), 8 gate + 8 filt co. x loads: 3 float4/ci
// (was 12 scalar). Gate weights from LDS (v2f), filt from global uniform
// (L1-hot). pk_fma inner loop, k-outer/t-inner order identical to R8.
template <int DIL>
__global__ __launch_bounds__(256) void layer_conv_kernel(
    const float* __restrict__ x, const float* __restrict__ wT,
    const float* __restrict__ conv_b, const float* __restrict__ pc,
    float* __restrict__ y, int layer) {
  __shared__ float wg_lds[192 * 8];  // [ci*3+k][col8] gate weights, 6 KB
  int tid = threadIdx.x;
  int g = blockIdx.y;
  int b = blockIdx.z;
  int l = blockIdx.x * 256 + tid;
  const float* wbase = wT + (size_t)(layer * 8 + g) * 3072;

  for (int idx = tid; idx < 1536; idx += 256) {
    // LDS [r][col8] <- wT [r][col16] cols 0..7 (gate)
    wg_lds[idx] = wbase[(idx >> 3) * 16 + (idx & 7)];
  }
  __syncthreads();

  const float* px = x + (size_t)(b * 64 * XS + XPAD + l) * 4;  // ci=0 row

  v2f ag[16], af[16];  // [t*4 + pair], pair p covers co j=2p,2p+1
#pragma unroll
  for (int q = 0; q < 16; ++q) {
    ag[q] = (v2f)(0.0f);
    af[q] = (v2f)(0.0f);
  }

  float4 xa[3], xb[3];  // [k] = 4 t values
  auto loadx = [&](float4* dst) {
    dst[0] = *(const float4*)(px - (size_t)DIL * 4);
    dst[1] = *(const float4*)px;
    dst[2] = *(const float4*)(px + (size_t)DIL * 4);
    px += (size_t)XS * 4;
  };
  auto compute = [&](int ci, const float4* xv) {
#pragma unroll
    for (int k = 0; k < 3; ++k) {
      const v2f* gw = (const v2f*)&wg_lds[(ci * 3 + k) * 8];
      const v2f* fw = (const v2f*)&wbase[(ci * 3 + k) * 16 + 8];
      v2f g0 = gw[0], g1 = gw[1], g2 = gw[2], g3 = gw[3];
      v2f f0 = fw[0], f1 = fw[1], f2 = fw[2], f3 = fw[3];
      const float* xk = (const float*)&xv[k];
#pragma unroll
      for (int t = 0; t < 4; ++t) {
        float xq = xk[t];
        v2f x2;
        x2.x = xq; x2.y = xq;
        ag[t * 4 + 0] += g0 * x2;
        ag[t * 4 + 1] += g1 * x2;
        ag[t * 4 + 2] += g2 * x2;
        ag[t * 4 + 3] += g3 * x2;
        af[t * 4 + 0] += f0 * x2;
        af[t * 4 + 1] += f1 * x2;
        af[t * 4 + 2] += f2 * x2;
        af[t * 4 + 3] += f3 * x2;
      }
    }
  };

  loadx(xa);
  for (int ci = 0; ci < 64; ci += 2) {
    loadx(xb);
    compute(ci, xa);
    if (ci + 2 < 64) loadx(xa);
    compute(ci + 1, xb);
  }

  const float SIG1 = 0.73105857863000489f;   // sigmoid(1) fp32
  const float TANH1 = 0.76159415595576486f;  // tanh(1) fp32
  bool lb = (l < DIL), rb = (l >= LL - DIL);
#pragma unroll
  for (int j = 0; j < 8; ++j) {
    int cog = g * 8 + j;
    int cof = 64 + g * 8 + j;
    const float* pg = pc + ((layer * 4 + b) * 128 + cog) * 3;
    const float* pf = pc + ((layer * 4 + b) * 128 + cof) * 3;
    float S0g = pg[0], S1g = pg[1], S2g = pg[2];
    float S0f = pf[0], S1f = pf[1], S2f = pf[2];
    float bg = conv_b[layer * 128 + cog] + S0g + S1g + S2g;
    float bf = conv_b[layer * 128 + cof] + S0f + S1f + S2f;
    bg -= (lb ? S0g : 0.0f) + (rb ? S2g : 0.0f);
    bf -= (lb ? S0f : 0.0f) + (rb ? S2f : 0.0f);
    float vg = 0.0f, vf = 0.0f;
    float4 o;
    float* op = (float*)&o;
#pragma unroll
    for (int t = 0; t < 4; ++t) {
      float av = ag[t * 4 + (j >> 1)][j & 1];
      float fv = af[t * 4 + (j >> 1)][j & 1];
      float sg = lif_step(vg, av + bg);
      float sf = lif_step(vf, fv + bf);
      float gv = (sg != 0.0f) ? SIG1 : 0.5f;
      float tv = (sf != 0.0f) ? TANH1 : 0.0f;
      op[t] = gv * tv;
    }
    *(float4*)&y[(size_t)((b * 64 + cog) * LL + l) * 4] = o;
  }
}

// ---------------- 1x1 skip / res convs ----------------
// grid (64, 2, 4): l-tile 64, cv (0=skip,1=res), b. block 256.
// Thread: 8 c x 2 l x 4 t register tile (32 v2f acc, t-paired pk_fma).
// Per cp: 2 w float4 + 2 y float4, prefetched 1 cp ahead. Sequential cp
// order = same summation order. No LDS.
__global__ __launch_bounds__(256) void skip_res_kernel(
    const float* __restrict__ y, const float* __restrict__ skipT,
    const float* __restrict__ resT, const float* __restrict__ skip_b,
    const float* __restrict__ res_b, float* __restrict__ tskip,
    float* __restrict__ x, int layer) {
  int tid = threadIdx.x;
  int lg = tid & 31;   // 32 l-groups of 2
  int cg = tid >> 5;   // 8 c-groups of 8
  int cv = blockIdx.y;
  int b = blockIdx.z;
  int l0 = blockIdx.x * 64 + lg * 2;
  int c0 = cg * 8;

  const float* wsrc = (cv ? resT : skipT) + layer * 4096 + c0;  // [cp][c]
  const float* yb = y + (size_t)(b * 64 * LL + l0) * 4;

  v2f acc[32];  // [c8][l2][t-pair2]
#pragma unroll
  for (int q = 0; q < 32; ++q) acc[q] = (v2f)(0.0f);

  float4 w0a = *(const float4*)&wsrc[0];
  float4 w1a = *(const float4*)&wsrc[4];
  float4 y0a = *(const float4*)yb;             // l0, t0..3
  float4 y1a = *(const float4*)(yb + 4);       // l0+1, t0..3

  for (int cp = 0; cp < 64; ++cp) {
    int cpn = (cp < 63) ? cp + 1 : 63;
    float4 w0b = *(const float4*)&wsrc[cpn * 64];
    float4 w1b = *(const float4*)&wsrc[cpn * 64 + 4];
    float4 y0b = *(const float4*)(yb + (size_t)cpn * LL * 4);
    float4 y1b = *(const float4*)(yb + (size_t)cpn * LL * 4 + 4);

    float wv[8] = {w0a.x, w0a.y, w0a.z, w0a.w, w1a.x, w1a.y, w1a.z, w1a.w};
    const v2f* yp0 = (const v2f*)&y0a;  // t01, t23
    const v2f* yp1 = (const v2f*)&y1a;
#pragma unroll
    for (int i = 0; i < 8; ++i) {
      v2f w2;
      w2.x = wv[i]; w2.y = wv[i];
      acc[i * 4 + 0] += w2 * yp0[0];
      acc[i * 4 + 1] += w2 * yp0[1];
      acc[i * 4 + 2] += w2 * yp1[0];
      acc[i * 4 + 3] += w2 * yp1[1];
    }
    w0a = w0b; w1a = w1b; y0a = y0b; y1a = y1b;
  }

  const float* bsrc = (cv ? res_b : skip_b) + layer * 64 + c0;
#pragma unroll
  for (int i = 0; i < 8; ++i) {
    float bb = bsrc[i];
    float r[8];  // [l2][t4]
#pragma unroll
    for (int q = 0; q < 4; ++q) {
      r[q * 2 + 0] = acc[i * 4 + q][0] + bb;
      r[q * 2 + 1] = acc[i * 4 + q][1] + bb;
    }
    // r[0..3] = l0 t0..3 (acc pairs 0,1); r[4..7] = l0+1 t0..3 (pairs 2,3)
    if (cv == 0) {
      size_t idx = (size_t)((b * 64 + c0 + i) * LL + l0) * 4;
      float4 o0, o1;
      if (layer == 0) {
        o0 = float4{0.f, 0.f, 0.f, 0.f};
        o1 = o0;
      } else {
        o0 = *(const float4*)&tskip[idx];
        o1 = *(const float4*)&tskip[idx + 4];
      }
      o0.x += r[0]; o0.y += r[1]; o0.z += r[2]; o0.w += r[3];
      o1.x += r[4]; o1.y += r[5]; o1.z += r[6]; o1.w += r[7];
      *(float4*)&tskip[idx] = o0;
      *(float4*)&tskip[idx + 4] = o1;
    } else {
      size_t idx = (size_t)((b * 64 + c0 + i) * XS + XPAD + l0) * 4;
      float4 o0 = *(const float4*)&x[idx];
      float4 o1 = *(const float4*)&x[idx + 4];
      o0.x += r[0]; o0.y += r[1]; o0.z += r[2]; o0.w += r[3];
      o1.x += r[4]; o1.y += r[5]; o1.z += r[6]; o1.w += r[7];
      *(float4*)&x[idx] = o0;
      *(float4*)&x[idx + 4] = o1;
    }
  }
}

// ---------------- output conv + LIF + sum over T ----------------
__global__ void out_kernel(const float* __restrict__ tskip,
                           const float* __restrict__ W_out,
                           const float* __restrict__ b_out,
                           float* __restrict__ out) {
  __shared__ float red[4][4][64];  // [grp][t][lq]
  int tid = threadIdx.x;
  int lq = tid & 63, grp = tid >> 6;
  int l = blockIdx.x * 64 + lq;
  int b = blockIdx.y;
  float acc[4] = {0.0f, 0.0f, 0.0f, 0.0f};
  for (int j = 0; j < 16; ++j) {
    int c = grp * 16 + j;
    float w = W_out[c];
    float4 sv = *(const float4*)&tskip[(size_t)((b * 64 + c) * LL + l) * 4];
    acc[0] += fmaxf(sv.x, 0.0f) * w;
    acc[1] += fmaxf(sv.y, 0.0f) * w;
    acc[2] += fmaxf(sv.z, 0.0f) * w;
    acc[3] += fmaxf(sv.w, 0.0f) * w;
  }
#pragma unroll
  for (int t = 0; t < 4; ++t) red[grp][t][lq] = acc[t];
  __syncthreads();
  if (grp == 0) {
    float bo = b_out[0];
    float v = 0.0f, s = 0.0f;
#pragma unroll
    for (int t = 0; t < 4; ++t) {
      float a = red[0][t][lq] + red[1][t][lq] + red[2][t][lq] + red[3][t][lq] + bo;
      s += lif_step(v, a);
    }
    out[b * LL + l] = s;
  }
}

extern "C" void kernel_launch(void* const* d_in, const int* in_sizes, int n_in,
                              void* d_out, int out_size, void* d_ws, size_t ws_size,
                              hipStream_t stream) {
  const float* audio   = (const float*)d_in[0];
  const int*   dstep   = (const int*)d_in[1];
  const float* W_in    = (const float*)d_in[2];
  const float* b_in    = (const float*)d_in[3];
  const float* demb_w1 = (const float*)d_in[4];
  const float* demb_b1 = (const float*)d_in[5];
  const float* demb_w2 = (const float*)d_in[6];
  const float* demb_b2 = (const float*)d_in[7];
  const float* dproj_w = (const float*)d_in[8];
  const float* dproj_b = (const float*)d_in[9];
  const float* conv_w  = (const float*)d_in[10];
  const float* conv_b  = (const float*)d_in[11];
  const float* skip_w  = (const float*)d_in[12];
  const float* skip_b  = (const float*)d_in[13];
  const float* res_w   = (const float*)d_in[14];
  const float* res_b   = (const float*)d_in[15];
  const float* W_out   = (const float*)d_in[16];
  const float* b_out   = (const float*)d_in[17];
  float* out = (float*)d_out;
  float* ws = (float*)d_ws;

  float* proj  = ws;                   // 2560
  float* skipT = proj + 2560;          // 40960
  float* resT  = skipT + 40960;        // 40960
  float* pc    = resT + 40960;         // 15360
  float* wT    = pc + 15360;           // 10*8*64*48 = 245760
  float* x     = wT + 245760;          // 4*64*5120*4 = 5242880
  float* y     = x + 5242880;          // 4*64*4096*4 = 4194304
  float* tskip = y + 4194304;          // 4194304

  prep_kernel<<<10, 256, 0, stream>>>(skip_w, res_w, conv_w, skipT, resT, wT);
  proj_kernel<<<10, 256, 0, stream>>>(dstep, demb_w1, demb_b1, demb_w2, demb_b2,
                                      dproj_w, dproj_b, proj);
  pc_kernel<<<dim3(10, 4), 128, 0, stream>>>(proj, conv_w, pc);
  padzero_kernel<<<256, 256, 0, stream>>>(x);
  encode_lif_kernel<<<dim3(64, 4), 256, 0, stream>>>(audio, W_in, b_in, x);

  for (int i = 0; i < NLAYERS; ++i) {
    dim3 gc(16, 8, 4);
    switch (i) {
      case 0: layer_conv_kernel<1><<<gc, 256, 0, stream>>>(x, wT, conv_b, pc, y, i); break;
      case 1: layer_conv_kernel<2><<<gc, 256, 0, stream>>>(x, wT, conv_b, pc, y, i); break;
      case 2: layer_conv_kernel<4><<<gc, 256, 0, stream>>>(x, wT, conv_b, pc, y, i); break;
      case 3: layer_conv_kernel<8><<<gc, 256, 0, stream>>>(x, wT, conv_b, pc, y, i); break;
      case 4: layer_conv_kernel<16><<<gc, 256, 0, stream>>>(x, wT, conv_b, pc, y, i); break;
      case 5: layer_conv_kernel<32><<<gc, 256, 0, stream>>>(x, wT, conv_b, pc, y, i); break;
      case 6: layer_conv_kernel<64><<<gc, 256, 0, stream>>>(x, wT, conv_b, pc, y, i); break;
      case 7: layer_conv_kernel<128><<<gc, 256, 0, stream>>>(x, wT, conv_b, pc, y, i); break;
      case 8: layer_conv_kernel<256><<<gc, 256, 0, stream>>>(x, wT, conv_b, pc, y, i); break;
      case 9: layer_conv_kernel<512><<<gc, 256, 0, stream>>>(x, wT, conv_b, pc, y, i); break;
    }
    skip_res_kernel<<<dim3(64, 2, 4), 256, 0, stream>>>(y, skipT, resT, skip_b,
                                                        res_b, tskip, x, i);
  }
  out_kernel<<<dim3(64, 4), 256, 0, stream>>>(tskip, W_out, b_out, out);
}